// Round 1
// 214.746 us; speedup vs baseline: 1.1931x; 1.1931x over previous
//
#include <hip/hip_runtime.h>
#include <stdint.h>

#define N_ 8192
#define D_ 1024
// logit = dot(imn,capn)/T; fp8 operands pre-scaled by 16 -> acc = 256*dot
#define EPILOGUE_SCALE (10.0f / 256.0f)
#define ENC_SCALE 16.0f
#define SLAB 262144  // bytes of one K-slab: 512 tiles x 512B fragments

typedef float f32x4 __attribute__((ext_vector_type(4)));

// async global->LDS, 16B per lane, LDS dest = wave-uniform base + lane*16
#define GLD16(gsrc, ldst)                                                    \
  __builtin_amdgcn_global_load_lds(                                          \
      (const __attribute__((address_space(1))) unsigned int*)(gsrc),         \
      (__attribute__((address_space(3))) unsigned int*)(ldst), 16, 0, 0)

// K=32 swizzled fragment layout (both operands), 8 MB each [R3/R5/R10-proven]:
//   byte addr = s*262144 + tile*512 + fl*8 + h*4
//   a wave's fragment (tile, s) is 64 lanes x 8B = 512B contiguous.

// Kernel 1 [unchanged this round]: normalize + fp8 encode + fragment-order
// stores. 512 blocks x 16 waves.
__global__ __launch_bounds__(1024) void normalize_k(
    const float* __restrict__ im, const float* __restrict__ cap,
    unsigned int* __restrict__ imn, unsigned int* __restrict__ capn,
    float* __restrict__ diag, float* __restrict__ sums /* rowsum|colsum */) {
  __shared__ unsigned int ldsA[16 * 257];
  __shared__ unsigned int ldsB[16 * 257];
  const int til = blockIdx.x;
  const int t = threadIdx.x;
  if (til < 4) ((float4*)sums)[til * 1024 + t] = (float4){0.f, 0.f, 0.f, 0.f};

  const int r = t >> 6, j = t & 63;   // wave r = row r of tile; lane j
  const int row = til * 16 + r;
  const float4* __restrict__ aR = (const float4*)(im + (size_t)row * D_);
  const float4* __restrict__ bR = (const float4*)(cap + (size_t)row * D_);

  float4 a0 = aR[j], a1 = aR[j + 64], a2 = aR[j + 128], a3 = aR[j + 192];
  float4 b0 = bR[j], b1 = bR[j + 64], b2 = bR[j + 128], b3 = bR[j + 192];

  float ssa = a0.x * a0.x + a0.y * a0.y + a0.z * a0.z + a0.w * a0.w
            + a1.x * a1.x + a1.y * a1.y + a1.z * a1.z + a1.w * a1.w
            + a2.x * a2.x + a2.y * a2.y + a2.z * a2.z + a2.w * a2.w
            + a3.x * a3.x + a3.y * a3.y + a3.z * a3.z + a3.w * a3.w;
  float ssb = b0.x * b0.x + b0.y * b0.y + b0.z * b0.z + b0.w * b0.w
            + b1.x * b1.x + b1.y * b1.y + b1.z * b1.z + b1.w * b1.w
            + b2.x * b2.x + b2.y * b2.y + b2.z * b2.z + b2.w * b2.w
            + b3.x * b3.x + b3.y * b3.y + b3.z * b3.z + b3.w * b3.w;
  float dt  = a0.x * b0.x + a0.y * b0.y + a0.z * b0.z + a0.w * b0.w
            + a1.x * b1.x + a1.y * b1.y + a1.z * b1.z + a1.w * b1.w
            + a2.x * b2.x + a2.y * b2.y + a2.z * b2.z + a2.w * b2.w
            + a3.x * b3.x + a3.y * b3.y + a3.z * b3.z + a3.w * b3.w;
#pragma unroll
  for (int o = 1; o < 64; o <<= 1) {  // full-wave butterfly (row = 1 wave)
    ssa += __shfl_xor(ssa, o, 64);
    ssb += __shfl_xor(ssb, o, 64);
    dt  += __shfl_xor(dt, o, 64);
  }
  const float ra = rsqrtf(ssa), rb = rsqrtf(ssb);
  if (j == 0) diag[row] = dt * ra * rb * 10.0f;
  const float sa = ra * ENC_SCALE, sb = rb * ENC_SCALE;

#define CVT_ST(av, bv, ofs)                                                  \
  {                                                                          \
    int pa_ = __builtin_amdgcn_cvt_pk_fp8_f32(av.x * sa, av.y * sa, 0, false); \
    pa_ = __builtin_amdgcn_cvt_pk_fp8_f32(av.z * sa, av.w * sa, pa_, true);  \
    int pb_ = __builtin_amdgcn_cvt_pk_fp8_f32(bv.x * sb, bv.y * sb, 0, false); \
    pb_ = __builtin_amdgcn_cvt_pk_fp8_f32(bv.z * sb, bv.w * sb, pb_, true);  \
    ldsA[r * 257 + j + (ofs)] = (unsigned int)pa_;                           \
    ldsB[r * 257 + j + (ofs)] = (unsigned int)pb_;                           \
  }
  CVT_ST(a0, b0, 0)
  CVT_ST(a1, b1, 64)
  CVT_ST(a2, b2, 128)
  CVT_ST(a3, b3, 192)
#undef CVT_ST
  __syncthreads();

  {
    const int s = t >> 5, c4 = t & 31;
    const int fl0 = c4 * 2, fl1 = fl0 + 1;
    const int i0 = (fl0 & 15) * 257 + s * 8 + (fl0 >> 4) * 2;
    const int i1 = (fl1 & 15) * 257 + s * 8 + (fl1 >> 4) * 2;
    uint4 va, vb;
    va.x = ldsA[i0]; va.y = ldsA[i0 + 1];
    va.z = ldsA[i1]; va.w = ldsA[i1 + 1];
    vb.x = ldsB[i0]; vb.y = ldsB[i0 + 1];
    vb.z = ldsB[i1]; vb.w = ldsB[i1 + 1];
    const size_t d = (size_t)s * 65536 + (size_t)til * 128 + c4 * 4;
    *(uint4*)(imn + d) = va;
    *(uint4*)(capn + d) = vb;
  }
}

// Kernel 2 [R12 rewrite]: ring-4 LDS pipeline (T3+T4). 256x256 block tile,
// 8 waves (2Mx4N), each wave a 128x64 slice. BK=64 (2 K-slabs). Stage-ahead-3
// via global_load_lds into a 4-deep LDS ring (128 KiB); counted vmcnt(12)
// never drains in the main loop; raw s_barrier (no __syncthreads vmcnt(0)
// drain). LDS keeps the fragment-contiguous layout -> ds_read_b64 is 2-way
// aliased = conflict-free, no swizzle needed. B-fragments now shared by all
// 8 waves (per-block vmem per K-tile 96KB -> 32KB).
__global__ __launch_bounds__(512, 2) void gemm_lse_k(
    const unsigned char* __restrict__ A,   // swizzled imn
    const unsigned char* __restrict__ B,   // swizzled capn
    float* __restrict__ rowsum, float* __restrict__ colsum) {
  __shared__ unsigned char lds[4][32768];  // ring-4: [A 16KB | B 16KB] each
  const int t = threadIdx.x;
  const int w = t >> 6, l = t & 63;

  // XCD/L2 swizzle: contiguous 128-block chunk per XCD, row-tile fastest.
  // 32 resident blocks/XCD = 4 rowT x 8 colT -> 1MB A + 2MB B < 4MB L2.
  const int bid = blockIdx.x + (blockIdx.y << 5);     // 0..1023
  const int nid = (bid & 7) * 128 + (bid >> 3);       // bijective (1024%8==0)
  const int rowT = ((nid >> 7) << 2) + (nid & 3);     // 0..31
  const int colT = (nid & 127) >> 2;                  // 0..31

  const size_t baseA = (size_t)rowT * 8192;  // 16 row-tiles x 512B per slab
  const size_t baseB = (size_t)colT * 8192;

  // staging roles: waves 0-3 fill the A half, waves 4-7 the B half.
  // 4 calls x 1KB per wave per K-tile = 4 vmem ops/thread/K-tile (uniform).
  const unsigned char* __restrict__ P = (w < 4) ? A : B;
  const size_t pbase = (w < 4) ? baseA : baseB;
  const int wo = (w & 3) * 4096;
  const int lhalf = (w < 4) ? 0 : 16384;

#define STAGE(kt, cb)                                                        \
  {                                                                          \
    const unsigned char* ps = P + (size_t)(kt) * (2 * (size_t)SLAB) + pbase; \
    _Pragma("unroll")                                                        \
    for (int c = 0; c < 4; ++c) {                                            \
      const int o = wo + c * 1024;                                           \
      GLD16(ps + (size_t)(o >> 13) * SLAB + (o & 8191) + l * 16,             \
            &lds[cb][lhalf + o]);                                            \
    }                                                                        \
  }

  const int wr = w >> 2, wc = w & 3;
  const int aoff = wr * 8 * 512 + l * 8;           // + si*8192 + m*512
  const int boff = 16384 + wc * 4 * 512 + l * 8;   // + si*8192 + n*512

  f32x4 acc[8][4];
#pragma unroll
  for (int m = 0; m < 8; ++m)
#pragma unroll
    for (int n = 0; n < 4; ++n) acc[m][n] = (f32x4){0.f, 0.f, 0.f, 0.f};

#define COMPUTE(cb)                                                          \
  {                                                                          \
    const unsigned char* Lc = &lds[cb][0];                                   \
    _Pragma("unroll")                                                        \
    for (int si = 0; si < 2; ++si) {                                         \
      long a_[8], b_[4];                                                     \
      _Pragma("unroll")                                                      \
      for (int m = 0; m < 8; ++m)                                            \
        a_[m] = *(const long*)(Lc + si * 8192 + aoff + m * 512);             \
      _Pragma("unroll")                                                      \
      for (int n = 0; n < 4; ++n)                                            \
        b_[n] = *(const long*)(Lc + si * 8192 + boff + n * 512);             \
      _Pragma("unroll")                                                      \
      for (int m = 0; m < 8; ++m)                                            \
        _Pragma("unroll")                                                    \
        for (int n = 0; n < 4; ++n)                                          \
          acc[m][n] = __builtin_amdgcn_mfma_f32_16x16x32_fp8_fp8(            \
              a_[m], b_[n], acc[m][n], 0, 0, 0);                             \
    }                                                                        \
  }

  // prologue: 3 K-tiles in flight (12 loads/thread outstanding)
  STAGE(0, 0)
  STAGE(1, 1)
  STAGE(2, 2)

  // main loop: stage(kt+3) targets buf[(kt-1)&3], freed at iter kt-1's end
  // barrier. vmcnt(12): wait own 4 loads of tile kt; 12 (tiles kt+1..kt+3)
  // stay in flight across both barriers.
#pragma unroll 1
  for (int kt = 0; kt < 13; ++kt) {
    STAGE(kt + 3, (kt + 3) & 3)
    asm volatile("s_waitcnt vmcnt(12)" ::: "memory");
    __builtin_amdgcn_s_barrier();
    COMPUTE(kt & 3)
    __builtin_amdgcn_s_barrier();
  }
  // tail: kt = 13,14,15 — drain 8 -> 4 -> 0
  asm volatile("s_waitcnt vmcnt(8)" ::: "memory");
  __builtin_amdgcn_s_barrier();
  COMPUTE(1)
  __builtin_amdgcn_s_barrier();
  asm volatile("s_waitcnt vmcnt(4)" ::: "memory");
  __builtin_amdgcn_s_barrier();
  COMPUTE(2)
  __builtin_amdgcn_s_barrier();
  asm volatile("s_waitcnt vmcnt(0)" ::: "memory");
  __builtin_amdgcn_s_barrier();
  COMPUTE(3)
#undef COMPUTE
#undef STAGE

  // epilogue: exp (fixed-max LSE; |logit| <= 10, no overflow possible)
#pragma unroll
  for (int m = 0; m < 8; ++m)
#pragma unroll
    for (int n = 0; n < 4; ++n)
#pragma unroll
      for (int r = 0; r < 4; ++r)
        acc[m][n][r] = __expf(acc[m][n][r] * EPILOGUE_SCALE);

  // C/D layout: col = lane&15, row = (lane>>4)*4 + reg  [measured m89/m91]
  const int rowBase = rowT * 256 + wr * 128;
  const int colBase = colT * 256 + wc * 64;
#pragma unroll
  for (int m = 0; m < 8; ++m)
#pragma unroll
    for (int r = 0; r < 4; ++r) {
      float v = 0.f;
#pragma unroll
      for (int n = 0; n < 4; ++n) v += acc[m][n][r];
      v += __shfl_xor(v, 1, 64);
      v += __shfl_xor(v, 2, 64);
      v += __shfl_xor(v, 4, 64);
      v += __shfl_xor(v, 8, 64);
      if ((l & 15) == 0)
        atomicAdd(&rowsum[rowBase + m * 16 + (l >> 4) * 4 + r], v);
    }
#pragma unroll
  for (int n = 0; n < 4; ++n) {
    float v = 0.f;
#pragma unroll
    for (int m = 0; m < 8; ++m)
      v += acc[m][n][0] + acc[m][n][1] + acc[m][n][2] + acc[m][n][3];
    v += __shfl_xor(v, 16, 64);
    v += __shfl_xor(v, 32, 64);
    if (l < 16)
      atomicAdd(&colsum[colBase + n * 16 + l], v);
  }
}

// Kernel 3: scalar reduce. [unchanged]
__global__ __launch_bounds__(256) void finalize_k(
    const float* __restrict__ rowsum, const float* __restrict__ colsum,
    const float* __restrict__ diag, float* __restrict__ out) {
  const int t = threadIdx.x;
  float lse = 0.f, dg = 0.f;
  for (int i = t; i < N_; i += 256) {
    lse += __logf(rowsum[i]) + __logf(colsum[i]);
    dg += diag[i];
  }
#pragma unroll
  for (int o = 32; o > 0; o >>= 1) {
    lse += __shfl_down(lse, o, 64);
    dg  += __shfl_down(dg, o, 64);
  }
  __shared__ float red[2][4];
  const int w = t >> 6, l = t & 63;
  if (l == 0) { red[0][w] = lse; red[1][w] = dg; }
  __syncthreads();
  if (t == 0) {
    lse = red[0][0] + red[0][1] + red[0][2] + red[0][3];
    dg  = red[1][0] + red[1][1] + red[1][2] + red[1][3];
    out[0] = 0.5f * lse / (float)N_ - dg / (float)N_;
  }
}

extern "C" void kernel_launch(void* const* d_in, const int* in_sizes, int n_in,
                              void* d_out, int out_size, void* d_ws, size_t ws_size,
                              hipStream_t stream) {
  const float* im = (const float*)d_in[0];
  const float* cap = (const float*)d_in[1];
  float* out = (float*)d_out;
  char* ws = (char*)d_ws;
  unsigned char* imn = (unsigned char*)ws;                 // 8 MB fp8 (swizzled)
  unsigned char* capn = imn + (size_t)N_ * D_;             // 8 MB fp8 (swizzled)
  float* rowsum = (float*)(ws + 2 * (size_t)N_ * D_);
  float* colsum = rowsum + N_;
  float* diag = colsum + N_;

  normalize_k<<<512, 1024, 0, stream>>>(im, cap, (unsigned int*)imn,
                                        (unsigned int*)capn, diag, rowsum);
  gemm_lse_k<<<dim3(32, 32), 512, 0, stream>>>(imn, capn, rowsum, colsum);
  finalize_k<<<1, 256, 0, stream>>>(rowsum, colsum, diag, out);
}